// Round 5
// baseline (1333.863 us; speedup 1.0000x reference)
//
#include <hip/hip_runtime.h>
#include <stdint.h>

// ModeloNeuralVasicek — two-phase mean-recursion.
// Round 21: R20 (8-step MFMA batching, 752us phase2) was VALU-issue bound:
// 62% active-CU VALUBusy at 1 wave/SIMD, ~38% stall, quarter-rate
// transcendentals + serial softplus chain. Changes:
// (1) 512 threads (8 waves, 2/SIMD): per-wave work halves (4 STAGE3 steps,
//     2 col-chunks / 8 MFMAs each); second wave fills issue stalls.
//     msum -> [mlp][qty=4q+e][w4] scalar layout: update hoist reads one
//     broadcast b128 per quantity + horizontal sum.
// (2) softplus linearized at anchor: softplus(z_a+d) ~ sp + sigma*d
//     (2nd-order err ~1e-7 << f16 noise). sp/sigma for 8 steps hoisted
//     off-chain; serial recursion per step = sub+2fma+2mul+2add (~20cy).
// Wave roles: wv = 4*mlp + 2*sg + half. STAGE3 steps J=4sg..4sg+3;
// MFMA cols 64*half+32*sg..+31 (chunks 2sg,2sg+1).

#define NSTEPS 2520
#define NB 64
#define NT 256
#define NQ 256
#define NMAT 7
#define NBODY 315
#define MWPAD 2544

typedef uint32_t u32x4 __attribute__((ext_vector_type(4)));
typedef float f32x4 __attribute__((ext_vector_type(4)));

__device__ __forceinline__ uint32_t rotl32(uint32_t v, int n) {
  return (v << n) | (v >> (32 - n));
}

// Threefry-2x32, 20 rounds — matches jax._src.prng.threefry2x32 exactly.
__device__ __forceinline__ void tf2x32(uint32_t k0, uint32_t k1,
                                       uint32_t x0, uint32_t x1,
                                       uint32_t& o0, uint32_t& o1) {
  const uint32_t k2 = k0 ^ k1 ^ 0x1BD11BDAu;
  x0 += k0; x1 += k1;
#define R4(a,b,c,d) \
  x0 += x1; x1 = rotl32(x1,(a)); x1 ^= x0; \
  x0 += x1; x1 = rotl32(x1,(b)); x1 ^= x0; \
  x0 += x1; x1 = rotl32(x1,(c)); x1 ^= x0; \
  x0 += x1; x1 = rotl32(x1,(d)); x1 ^= x0;
  R4(13,15,26,6)  x0 += k1; x1 += k2 + 1u;
  R4(17,29,16,24) x0 += k2; x1 += k0 + 2u;
  R4(13,15,26,6)  x0 += k0; x1 += k1 + 3u;
  R4(17,29,16,24) x0 += k1; x1 += k2 + 4u;
  R4(13,15,26,6)  x0 += k2; x1 += k0 + 5u;
#undef R4
  o0 = x0; o1 = x1;
}

// fast reciprocal: v_rcp + one Newton step (~1e-7 rel; replaces full f32 div)
__device__ __forceinline__ float fast_rcp(float q) {
  float r = __builtin_amdgcn_rcpf(q);
  r = __builtin_fmaf(r, __builtin_fmaf(-q, r, 1.0f), r);
  return r;
}

// Eigen/XLA generic_fast_tanh_float (preamble only; keep full precision).
__device__ __forceinline__ float eigen_tanh(float a_x) {
  float x = fminf(fmaxf(a_x, -7.90531110763549805f), 7.90531110763549805f);
  float x2 = x * x;
  float p = __builtin_fmaf(x2, -2.76076847742355e-16f, 2.00018790482477e-13f);
  p = __builtin_fmaf(x2, p, -8.60467152213735e-11f);
  p = __builtin_fmaf(x2, p, 5.12229709037114e-08f);
  p = __builtin_fmaf(x2, p, 1.48572235717979e-05f);
  p = __builtin_fmaf(x2, p, 6.37261928875436e-04f);
  p = __builtin_fmaf(x2, p, 4.89352455891786e-03f);
  p = x * p;
  float q = __builtin_fmaf(x2, 1.19825839466702e-06f, 1.18534705686654e-04f);
  q = __builtin_fmaf(x2, q, 2.26843463243900e-03f);
  q = __builtin_fmaf(x2, q, 4.89352518554385e-03f);
  float rr = p / q;
  return (fabsf(a_x) < 0.0004f) ? a_x : rr;
}

// Eigen/XLA erf polynomial with rcp-division (scan loop hot path).
__device__ __forceinline__ float eigen_erf_fast(float a_x) {
  float x = fminf(fmaxf(a_x, -4.0f), 4.0f);
  float x2 = x * x;
  float p = __builtin_fmaf(x2, -2.72614225801306e-10f, 2.77068142495902e-08f);
  p = __builtin_fmaf(x2, p, -2.10102402082508e-06f);
  p = __builtin_fmaf(x2, p, -5.69250639462346e-05f);
  p = __builtin_fmaf(x2, p, -7.34990630326855e-04f);
  p = __builtin_fmaf(x2, p, -2.95459980854025e-03f);
  p = __builtin_fmaf(x2, p, -1.60960333262415e-02f);
  p = x * p;
  float q = __builtin_fmaf(x2, -1.45660718464996e-05f, -2.13374055278905e-04f);
  q = __builtin_fmaf(x2, q, -1.68282697438203e-03f);
  q = __builtin_fmaf(x2, q, -7.37332916720468e-03f);
  q = __builtin_fmaf(x2, q, -1.42647390514189e-02f);
  return p * fast_rcp(q);
}

// fast softplus: __expf/__logf (v_exp/v_log based), abs err ~1e-6
__device__ __forceinline__ float softplus_fast(float x) {
  float e = __expf(-fabsf(x));
  return fmaxf(x, 0.0f) + __logf(1.0f + e);
}

// XLA chlo.erf_inv f32 (Giles polynomial) — phase 1 only, keep exact.
__device__ __forceinline__ float erfinv_xla(float x) {
  float w = -logf((1.0f - x) * (1.0f + x));
  float p;
  if (w < 5.0f) {
    w = w - 2.5f;
    p = 2.81022636e-08f;
    p = __builtin_fmaf(p, w, 3.43273939e-07f);
    p = __builtin_fmaf(p, w, -3.5233877e-06f);
    p = __builtin_fmaf(p, w, -4.39150654e-06f);
    p = __builtin_fmaf(p, w, 0.00021858087f);
    p = __builtin_fmaf(p, w, -0.00125372503f);
    p = __builtin_fmaf(p, w, -0.00417768164f);
    p = __builtin_fmaf(p, w, 0.246640727f);
    p = __builtin_fmaf(p, w, 1.50140941f);
  } else {
    w = sqrtf(w) - 3.0f;
    p = -0.000200214257f;
    p = __builtin_fmaf(p, w, 0.000100950558f);
    p = __builtin_fmaf(p, w, 0.00134934322f);
    p = __builtin_fmaf(p, w, -0.00367342844f);
    p = __builtin_fmaf(p, w, 0.00573950773f);
    p = __builtin_fmaf(p, w, -0.0076224613f);
    p = __builtin_fmaf(p, w, 0.00943887047f);
    p = __builtin_fmaf(p, w, 1.00167406f);
    p = __builtin_fmaf(p, w, 2.83297682f);
  }
  return p * x;
}

__device__ __forceinline__ float bits_to_normal(uint32_t bits) {
  const float MINVAL = -0.999999940395355224609375f;
  uint32_t fb = (bits >> 9) | 0x3F800000u;
  float f01 = __uint_as_float(fb) - 1.0f;
  float u = f01 * 2.0f + MINVAL;
  u = fmaxf(u, MINVAL);
  return 1.41421356237309515f * erfinv_xla(u);
}

__device__ __forceinline__ uint16_t f32_to_f16bits(float x) {
  _Float16 hv = (_Float16)x;  // RNE
  return __builtin_bit_cast(uint16_t, hv);
}

__device__ __forceinline__ uint32_t pack_f16x2(float lo, float hi) {
  return (uint32_t)f32_to_f16bits(lo) | ((uint32_t)f32_to_f16bits(hi) << 16);
}

// DPP add: v += dpp_move(v) — VALU pipe. 0x111..0x118 = row_shr 1..8.
template <int CTRL, int RMASK>
__device__ __forceinline__ float dpp_add(float v) {
  int x = __builtin_amdgcn_update_dpp(0, __float_as_int(v), CTRL, RMASK, 0xf, true);
  return v + __int_as_float(x);
}

#define DTF  0.00396825396825396826f
#define SQDT 0.06299407883487120442f
#define TSTEP (1.0f / 2519.0f)
// tangents scaled by 64 for f16 headroom; update folds the 1/64 back in
#define TSC      64.0f
#define TSC_INV  0.015625f
#define INV_SQRT2 0.7071067811865475f
#define PHI_C     0.3989422804014327f

// ---------------- Phase 1: mean_dW[b][s] — fully parallel ----------------
__global__ __launch_bounds__(256)
void vasicek_phase1_meandw(float* __restrict__ ws) {
  const int tid = threadIdx.x;
  const int lane = tid & 63;
  const int wv = tid >> 6;
  const int wid = blockIdx.x * 4 + wv;          // 0 .. 64*2520-1
  const int b = wid / NSTEPS;
  const int s = wid - b * NSTEPS;

  uint32_t kA, kB;
  tf2x32(0u, 1u, 0u, (uint32_t)s, kA, kB);      // split(key(1))[s]

  float sum = 0.f;
#pragma unroll
  for (int i = 0; i < 4; ++i) {
    uint32_t cnt = (uint32_t)(b * NQ + lane + i * 64);
    uint32_t q0, q1;
    tf2x32(kA, kB, 0u, cnt, q0, q1);
    float dw = bits_to_normal(q0 ^ q1) * SQDT;
    sum += dw;
  }
  sum += __shfl_xor(sum, 32, 64); sum += __shfl_xor(sum, 16, 64);
  sum += __shfl_xor(sum, 8, 64);  sum += __shfl_xor(sum, 4, 64);
  sum += __shfl_xor(sum, 2, 64);  sum += __shfl_xor(sum, 1, 64);
  if (lane == 0) ws[b * NSTEPS + s] = sum * (1.0f / 256.0f);
}

// ---- B-fragment machinery, k-PERMUTED (unchanged pairing from R17-R20):
// B dword d of K-chunk T (lane q,n) holds W2 rows (16T+4q+d, 64+16T+4q+d)
// at column 64*half + 32*sg + 16*C + n (this wave's 2 col-chunks).
#define BDECL(T, C) u32x4 b_##T##_##C;
#define BINIT(T, C) { \
  const int col_ = 16 * (4 * half + 2 * sg + (C)) + n; \
  const int r0_ = 16 * (T) + 4 * q; \
  b_##T##_##C = (u32x4){ \
    pack_f16x2(W2src[(r0_ + 0) * 128 + col_], W2src[(r0_ + 64) * 128 + col_]), \
    pack_f16x2(W2src[(r0_ + 1) * 128 + col_], W2src[(r0_ + 65) * 128 + col_]), \
    pack_f16x2(W2src[(r0_ + 2) * 128 + col_], W2src[(r0_ + 66) * 128 + col_]), \
    pack_f16x2(W2src[(r0_ + 3) * 128 + col_], W2src[(r0_ + 67) * 128 + col_])}; \
  asm volatile("" : "+a"(b_##T##_##C)); /* pin in AGPR quad */ \
}
#define MFMA1(ACC, AF, BF) \
  asm("v_mfma_f32_16x16x32_f16 %0, %1, %2, %0" : "+v"(ACC) : "v"(AF), "a"(BF));

// layer-1 for step (J of batch), time TV, anchor RANCH; writes f16 halves of
// regions 2J (value) and 2J+1 (tangent*64) for this wave's jH element.
#define STAGE3S(TV, SLOT, J, RANCH) { \
  float pre_ = __builtin_fmaf((TV), w11, __builtin_fmaf((RANCH), w10, c1)); \
  float e_ = eigen_erf_fast(pre_ * INV_SQRT2); \
  float cg_ = (e_ + 1.0f) * 0.5f; \
  float v_ = pre_ * cg_; \
  float ph_ = PHI_C * __expf(-0.5f * pre_ * pre_); \
  float d_ = __builtin_fmaf(pre_, ph_, cg_) * w10S; \
  ((uint16_t*)&h1x[SLOT][mlp][2*(J)][0])[2 * lane + half] = f32_to_f16bits(v_); \
  ((uint16_t*)&h1x[SLOT][mlp][2*(J)+1][0])[2 * lane + half] = f32_to_f16bits(d_); \
}

// epilogue for one col-chunk: acc elems e = (step 2q+(e>>1), type e&1)
#define EPI(AC, BC, WC) { \
  float yv0 = AC[0] + (BC); float yt0 = AC[1]; \
  float yv1 = AC[2] + (BC); float yt1 = AC[3]; \
  float e0 = eigen_erf_fast(yv0 * INV_SQRT2); float c0_ = (e0 + 1.0f) * 0.5f; \
  float e1 = eigen_erf_fast(yv1 * INV_SQRT2); float c1_ = (e1 + 1.0f) * 0.5f; \
  pv0 = __builtin_fmaf((WC) * yv0, c0_, pv0); \
  pv1 = __builtin_fmaf((WC) * yv1, c1_, pv1); \
  float p0_ = PHI_C * __expf(-0.5f * yv0 * yv0); \
  float p1_ = PHI_C * __expf(-0.5f * yv1 * yv1); \
  float g0_ = __builtin_fmaf(yv0, p0_, c0_); \
  float g1_ = __builtin_fmaf(yv1, p1_, c1_); \
  pt0 = __builtin_fmaf((WC) * g0_, yt0, pt0); \
  pt1 = __builtin_fmaf((WC) * g1_, yt1, pt1); \
}

#define DPPROW(CTRL) { \
  pv0 = dpp_add<CTRL, 0xf>(pv0); pt0 = dpp_add<CTRL, 0xf>(pt0); \
  pv1 = dpp_add<CTRL, 0xf>(pv1); pt1 = dpp_add<CTRL, 0xf>(pt1); }

// ---------------- Phase 2: scan, 64 blocks x 512 ---------------------------
__global__
__attribute__((amdgpu_flat_work_group_size(512, 512)))
void vasicek_phase2_scan(
    const float* __restrict__ X, const float* __restrict__ r_ult,
    const float* __restrict__ mats,
    const float* __restrict__ Wp, const float* __restrict__ bp,
    const float* __restrict__ ln_g, const float* __restrict__ ln_b,
    const float* __restrict__ muW1, const float* __restrict__ mub1,
    const float* __restrict__ muW2, const float* __restrict__ mub2,
    const float* __restrict__ muW3, const float* __restrict__ mub3,
    const float* __restrict__ siW1, const float* __restrict__ sib1,
    const float* __restrict__ siW2, const float* __restrict__ sib2,
    const float* __restrict__ siW3, const float* __restrict__ sib3,
    const float* __restrict__ ws, float* __restrict__ out) {
  // [slot][mlp][region n = 2*step+type][68 dw] (region stride 272B == 16 mod 128)
  __shared__ __align__(16) uint32_t h1x[2][2][16][68];
  __shared__ __align__(16) float meanw[MWPAD];
  __shared__ float part[256];
  __shared__ float mbuf[64];
  __shared__ float ctx_lds[192];
  // [slot][mlp][qty = 4q+e][w4] — one b128 per qty gives the 4 summands
  __shared__ __align__(16) float msum[2][2][16][4];

  const int t = threadIdx.x;
  const int b = blockIdx.x;
  const int lane = t & 63;
  const int wv = t >> 6;

  for (int i = t; i < MWPAD; i += 512)
    meanw[i] = i < NSTEPS ? ws[b * NSTEPS + i] : 0.f;

  // ---- context aggregator (threads 0..255, one T-row each) ----
  float h[64];
  if (t < 256) {
    float x0 = X[(b * NT + t) * 2 + 0];
    float x1 = X[(b * NT + t) * 2 + 1];
    float s = 0.f;
#pragma unroll
    for (int c = 0; c < 64; ++c) {
      float pre = __builtin_fmaf(x1, Wp[64 + c], x0 * Wp[c]) + bp[c];
      h[c] = eigen_tanh(pre);
      s += h[c];
    }
    float m = s * 0.015625f;
    float vs = 0.f;
#pragma unroll
    for (int c = 0; c < 64; ++c) { float d = h[c] - m; vs = __builtin_fmaf(d, d, vs); }
    float den = sqrtf(vs * 0.015625f + 1e-5f);
#pragma unroll
    for (int c = 0; c < 64; ++c)
      h[c] = ((h[c] - m) / den) * ln_g[c] + ln_b[c];
#pragma unroll
    for (int c = 0; c < 64; ++c) {
      float v = h[c];
      v += __shfl_xor(v, 32, 64); v += __shfl_xor(v, 16, 64);
      v += __shfl_xor(v, 8, 64);  v += __shfl_xor(v, 4, 64);
      v += __shfl_xor(v, 2, 64);  v += __shfl_xor(v, 1, 64);
      if (lane == 0) part[wv * 64 + c] = v;
    }
  }
  __syncthreads();
  if (t < 64) {
    float m = ((part[t] + part[64 + t]) + (part[128 + t] + part[192 + t])) * (1.0f / 256.0f);
    mbuf[t] = m;
    ctx_lds[t] = m;
  }
  __syncthreads();
  if (t < 256) {
#pragma unroll
    for (int c = 0; c < 64; ++c) {
      float d = h[c] - mbuf[c];
      float v = d * d;
      v += __shfl_xor(v, 32, 64); v += __shfl_xor(v, 16, 64);
      v += __shfl_xor(v, 8, 64);  v += __shfl_xor(v, 4, 64);
      v += __shfl_xor(v, 2, 64);  v += __shfl_xor(v, 1, 64);
      if (lane == 0) part[wv * 64 + c] = v;
    }
    if (t == 255) {
#pragma unroll
      for (int c = 0; c < 64; ++c) ctx_lds[128 + c] = h[c];
    }
  }
  __syncthreads();
  if (t < 64) {
    float vs = (part[t] + part[64 + t]) + (part[128 + t] + part[192 + t]);
    ctx_lds[64 + t] = sqrtf(vs / 255.0f);
  }
  __syncthreads();

  // ---- per-wave roles: wv = 4*mlp + 2*sg + half ----
  const int mlp = wv >> 2;
  const int sg = (wv >> 1) & 1;
  const int half = wv & 1;
  const int jH = 64 * half + lane;            // layer-1 element ownership
  const float* W1 = mlp == 0 ? muW1 : siW1;
  const float* W2src = mlp == 0 ? muW2 : siW2;
  float c1 = (mlp == 0 ? mub1 : sib1)[jH];
  for (int c = 0; c < 192; ++c) {
    const float cx = ctx_lds[c];
    c1 = __builtin_fmaf(cx, W1[(2 + c) * 128 + jH], c1);
  }
  const float w10 = W1[jH], w11 = W1[128 + jH];
  const float w10S = w10 * TSC;
  const float b3mu = mub3[0], b3si = sib3[0];

  const int q = lane >> 4, n = lane & 15;
  const int w4 = wv & 3;

  // per-lane epilogue constants for its 2 col-chunks
  const float* b2p = mlp == 0 ? mub2 : sib2;
  const float* w3p = mlp == 0 ? muW3 : siW3;
  const int colb = 64 * half + 32 * sg + n;
  const float b2C0 = b2p[colb],      w3C0 = w3p[colb];
  const float b2C1 = b2p[colb + 16], w3C1 = w3p[colb + 16];

  // this wave's 2 col-tiles of its W2 -> 8 AGPR quads (one-time; pinned)
  BDECL(0,0) BDECL(0,1) BDECL(1,0) BDECL(1,1)
  BDECL(2,0) BDECL(2,1) BDECL(3,0) BDECL(3,1)
  BINIT(0,0) BINIT(0,1) BINIT(1,0) BINIT(1,1)
  BINIT(2,0) BINIT(2,1) BINIT(3,0) BINIT(3,1)

  // A-frag base pointers: region n of this wave's MLP, quad offset q.
  // region stride 68 dw = 17 u32x4; af_T at +4T quads.
  const u32x4* hq0 = ((const u32x4*)&h1x[0][mlp][0][0]) + 17 * n + q;
  const u32x4* hq1 = ((const u32x4*)&h1x[1][mlp][0][0]) + 17 * n + q;

  float r = r_ult[b];
  float area = 0.f;
  float aA[8], aB[8];
  float mu_c = 0.f, si_c = 0.f;

  // ---- prologue: layer-1 for batch 0 (steps 0..7), anchor r0 -> slot 0 ----
#pragma unroll
  for (int j = 0; j < 8; ++j) {
    aB[j] = r;
    aA[j] = r;
    if ((j >> 2) == sg) {
      const float tv0 = TSTEP * (float)j;
      STAGE3S(tv0, 0, j, r)
    }
  }
  __syncthreads();

  // ---- main loop: body k: updates batch k, MFMA batch k+1, STAGE3 batch k+2
#pragma unroll 1
  for (int k = -1; k < NBODY; ++k) {
    const int sl = k & 1;        // msum slot (batch k); h1 write slot (batch k+2)
    const int so = sl ^ 1;       // h1 read slot (batch k+1); msum write slot

    const u32x4* hq = so ? hq1 : hq0;
    u32x4 af0 = hq[0], af1 = hq[4], af2 = hq[8], af3 = hq[12];

    const int u0 = k < 0 ? 0 : 8 * k;
    f32x4 mwa = *(const f32x4*)&meanw[u0];
    f32x4 mwb = *(const f32x4*)&meanw[u0 + 4];
    f32x4 mp0 = *(const f32x4*)&meanw[u0 + 8];
    f32x4 mp1 = *(const f32x4*)&meanw[u0 + 12];
    f32x4 mp2 = *(const f32x4*)&meanw[u0 + 16];
    f32x4 mp3 = *(const f32x4*)&meanw[u0 + 20];

    // MFMA batch k+1 (matrix pipe; overlaps all the VALU work below)
    f32x4 ac0 = {0,0,0,0}, ac1 = {0,0,0,0};
    MFMA1(ac0, af0, b_0_0) MFMA1(ac1, af0, b_0_1)
    MFMA1(ac0, af1, b_1_0) MFMA1(ac1, af1, b_1_1)
    MFMA1(ac0, af2, b_2_0) MFMA1(ac1, af2, b_2_1)
    MFMA1(ac0, af3, b_3_0) MFMA1(ac1, af3, b_3_1)

    // ---- update hoist: per-step linearized coefficients (off-chain) ----
    float mua[8], mutP[8], spP[8], stP[8];
#pragma unroll
    for (int j = 0; j < 8; ++j) {
      const int qv = 4 * (j >> 1) + 2 * (j & 1);
      f32x4 xm = *(const f32x4*)&msum[sl][0][qv][0];
      f32x4 xt = *(const f32x4*)&msum[sl][0][qv + 1][0];
      f32x4 xs = *(const f32x4*)&msum[sl][1][qv][0];
      f32x4 xu = *(const f32x4*)&msum[sl][1][qv + 1][0];
      mua[j]  = ((xm[0] + xm[1]) + (xm[2] + xm[3])) + b3mu;
      mutP[j] = ((xt[0] + xt[1]) + (xt[2] + xt[3])) * TSC_INV;
      float z = ((xs[0] + xs[1]) + (xs[2] + xs[3])) + b3si;
      float sit = ((xu[0] + xu[1]) + (xu[2] + xu[3])) * TSC_INV;
      float e_ = __expf(-fabsf(z));
      float sp = fmaxf(z, 0.f) + __logf(1.0f + e_);
      float inv = fast_rcp(1.0f + e_);
      float sgm = z > 0.f ? inv : 1.0f - inv;
      spP[j] = sp + 1e-5f;
      stP[j] = sgm * sit;
    }

    // serial updates for batch k (steps 8k..8k+7): short fma chain only
    if (k >= 0) {
      const float mwU[8] = {mwa[0], mwa[1], mwa[2], mwa[3],
                            mwb[0], mwb[1], mwb[2], mwb[3]};
#pragma unroll
      for (int j = 0; j < 8; ++j) {
        float dru = r - aA[j];
        float mu = __builtin_fmaf(mutP[j], dru, mua[j]);
        float si = __builtin_fmaf(stP[j], dru, spP[j]);
        r = __fadd_rn(__fadd_rn(r, __fmul_rn(mu, DTF)), __fmul_rn(si, mwU[j]));
        area = __fadd_rn(area, __fmul_rn(r, DTF));
        if (j == 7) { mu_c = mu; si_c = si; }
      }
    }
#pragma unroll
    for (int j = 0; j < 8; ++j) aA[j] = aB[j];

    // STAGE3 batch k+2 (steps 8k+16..8k+23) at predicted anchors
    {
      const float rE = r;
      const float mwP[16] = {mp0[0], mp0[1], mp0[2], mp0[3],
                             mp1[0], mp1[1], mp1[2], mp1[3],
                             mp2[0], mp2[1], mp2[2], mp2[3],
                             mp3[0], mp3[1], mp3[2], mp3[3]};
      float S = ((mwP[0] + mwP[1]) + (mwP[2] + mwP[3])) +
                ((mwP[4] + mwP[5]) + (mwP[6] + mwP[7]));
#pragma unroll
      for (int j = 0; j < 8; ++j) {
        if (j > 0) S += mwP[7 + j];
        float aj = __builtin_fmaf(mu_c, DTF * (float)(8 + j), rE);
        aj = __builtin_fmaf(si_c, S, aj);
        aB[j] = aj;
        if ((j >> 2) == sg) {
          const float tv = TSTEP * (float)(8 * k + 16 + j);
          STAGE3S(tv, sl, j, aj)
        }
      }
    }

    // MFMA dst -> VALU read hazard fence
    asm volatile("s_nop 7\n\ts_nop 7" : "+v"(ac0), "+v"(ac1));

    // epilogue batch k+1: gelu2 val+tan, per-row (16-lane) DPP reduce
    float pv0 = 0.f, pt0 = 0.f, pv1 = 0.f, pt1 = 0.f;
    EPI(ac0, b2C0, w3C0) EPI(ac1, b2C1, w3C1)
    DPPROW(0x111) DPPROW(0x112) DPPROW(0x114) DPPROW(0x118)
    if (n == 15) {
      float* mr = &msum[so][mlp][4 * q][0];
      mr[0 + w4]  = pv0;   // qty 4q+0 = (step 2q,   val)
      mr[4 + w4]  = pt0;   // qty 4q+1 = (step 2q,   tan)
      mr[8 + w4]  = pv1;   // qty 4q+2 = (step 2q+1, val)
      mr[12 + w4] = pt1;   // qty 4q+3 = (step 2q+1, tan)
    }
    __syncthreads();  // publish msum[so] (batch k+1) + h1x[sl] (batch k+2)
  }

  if (t < NMAT) {
    float mx = mats[0];
#pragma unroll
    for (int i = 1; i < NMAT; ++i) mx = fmaxf(mx, mats[i]);
    const float mm = mats[t];
    const float frac = mm / (mx + 1e-12f);
    out[b * NMAT + t] = (area * frac) / (mm + 1e-12f);
  }
}

extern "C" void kernel_launch(void* const* d_in, const int* in_sizes, int n_in,
                              void* d_out, int out_size, void* d_ws, size_t ws_size,
                              hipStream_t stream) {
  (void)in_sizes; (void)n_in; (void)ws_size; (void)out_size;
  const float* X      = (const float*)d_in[0];
  const float* r_ult  = (const float*)d_in[1];
  const float* mats   = (const float*)d_in[2];
  const float* Wp     = (const float*)d_in[3];
  const float* bp     = (const float*)d_in[4];
  const float* ln_g   = (const float*)d_in[5];
  const float* ln_b   = (const float*)d_in[6];
  const float* muW1   = (const float*)d_in[7];
  const float* mub1   = (const float*)d_in[8];
  const float* muW2   = (const float*)d_in[9];
  const float* mub2   = (const float*)d_in[10];
  const float* muW3   = (const float*)d_in[11];
  const float* mub3   = (const float*)d_in[12];
  const float* siW1   = (const float*)d_in[13];
  const float* sib1   = (const float*)d_in[14];
  const float* siW2   = (const float*)d_in[15];
  const float* sib2   = (const float*)d_in[16];
  const float* siW3   = (const float*)d_in[17];
  const float* sib3   = (const float*)d_in[18];
  float* ws = (float*)d_ws;   // 64*2520*4 = 645,120 bytes

  hipLaunchKernelGGL(vasicek_phase1_meandw,
                     dim3(NB * NSTEPS / 4), dim3(256), 0, stream, ws);
  hipLaunchKernelGGL(vasicek_phase2_scan,
                     dim3(NB), dim3(512), 0, stream,
                     X, r_ult, mats, Wp, bp, ln_g, ln_b,
                     muW1, mub1, muW2, mub2, muW3, mub3,
                     siW1, sib1, siW2, sib2, siW3, sib3,
                     ws, (float*)d_out);
}

// Round 6
// 720.976 us; speedup vs baseline: 1.8501x; 1.8501x over previous
//
#include <hip/hip_runtime.h>
#include <stdint.h>

// ModeloNeuralVasicek — two-phase mean-recursion.
// Round 22: affine-scan core. R21 post-mortem: hoist+serial replicated in 8
// waves + 32 b128 msum reads -> LDS-unit + VALU both worse. Back to R20's
// 4-wave structure, but the scan is restructured around the fact that each
// step is AFFINE in r (tangent-linearized MLP + linearized softplus):
//   r_{s+1} = beta_s*r + alpha_s,  beta/alpha r-independent.
// - lane j computes (beta_j, alpha_j) for step j (4 per-lane b128 msum reads)
// - DPP affine prefix-scan (3 rounds, identity via update_dpp old/bound=false)
//   -> rho_j for all 8 steps; r_next = readlane(rho,7): serial chain = 1 fma
// - area accumulated per-lane (rho*DT), reduced once after the loop
// - ONE anchor per batch (drift-only prediction, dist 16-23; tangent corrects)
//   kept in 4 uniform floats; STAGE3 base = fma(a,w10,c1) hoisted per body
// - STAGE3 (batch k+2) uses previous body's anchor -> issues at body start

#define NSTEPS 2520
#define NB 64
#define NT 256
#define NQ 256
#define NMAT 7
#define NBODY 315
#define MWPAD 2544

typedef uint32_t u32x4 __attribute__((ext_vector_type(4)));
typedef float f32x4 __attribute__((ext_vector_type(4)));

__device__ __forceinline__ uint32_t rotl32(uint32_t v, int n) {
  return (v << n) | (v >> (32 - n));
}

// Threefry-2x32, 20 rounds — matches jax._src.prng.threefry2x32 exactly.
__device__ __forceinline__ void tf2x32(uint32_t k0, uint32_t k1,
                                       uint32_t x0, uint32_t x1,
                                       uint32_t& o0, uint32_t& o1) {
  const uint32_t k2 = k0 ^ k1 ^ 0x1BD11BDAu;
  x0 += k0; x1 += k1;
#define R4(a,b,c,d) \
  x0 += x1; x1 = rotl32(x1,(a)); x1 ^= x0; \
  x0 += x1; x1 = rotl32(x1,(b)); x1 ^= x0; \
  x0 += x1; x1 = rotl32(x1,(c)); x1 ^= x0; \
  x0 += x1; x1 = rotl32(x1,(d)); x1 ^= x0;
  R4(13,15,26,6)  x0 += k1; x1 += k2 + 1u;
  R4(17,29,16,24) x0 += k2; x1 += k0 + 2u;
  R4(13,15,26,6)  x0 += k0; x1 += k1 + 3u;
  R4(17,29,16,24) x0 += k1; x1 += k2 + 4u;
  R4(13,15,26,6)  x0 += k2; x1 += k0 + 5u;
#undef R4
  o0 = x0; o1 = x1;
}

// fast reciprocal: v_rcp + one Newton step (~1e-7 rel; replaces full f32 div)
__device__ __forceinline__ float fast_rcp(float q) {
  float r = __builtin_amdgcn_rcpf(q);
  r = __builtin_fmaf(r, __builtin_fmaf(-q, r, 1.0f), r);
  return r;
}

// Eigen/XLA generic_fast_tanh_float (preamble only; keep full precision).
__device__ __forceinline__ float eigen_tanh(float a_x) {
  float x = fminf(fmaxf(a_x, -7.90531110763549805f), 7.90531110763549805f);
  float x2 = x * x;
  float p = __builtin_fmaf(x2, -2.76076847742355e-16f, 2.00018790482477e-13f);
  p = __builtin_fmaf(x2, p, -8.60467152213735e-11f);
  p = __builtin_fmaf(x2, p, 5.12229709037114e-08f);
  p = __builtin_fmaf(x2, p, 1.48572235717979e-05f);
  p = __builtin_fmaf(x2, p, 6.37261928875436e-04f);
  p = __builtin_fmaf(x2, p, 4.89352455891786e-03f);
  p = x * p;
  float q = __builtin_fmaf(x2, 1.19825839466702e-06f, 1.18534705686654e-04f);
  q = __builtin_fmaf(x2, q, 2.26843463243900e-03f);
  q = __builtin_fmaf(x2, q, 4.89352518554385e-03f);
  float rr = p / q;
  return (fabsf(a_x) < 0.0004f) ? a_x : rr;
}

// Eigen/XLA erf polynomial with rcp-division (scan loop hot path).
__device__ __forceinline__ float eigen_erf_fast(float a_x) {
  float x = fminf(fmaxf(a_x, -4.0f), 4.0f);
  float x2 = x * x;
  float p = __builtin_fmaf(x2, -2.72614225801306e-10f, 2.77068142495902e-08f);
  p = __builtin_fmaf(x2, p, -2.10102402082508e-06f);
  p = __builtin_fmaf(x2, p, -5.69250639462346e-05f);
  p = __builtin_fmaf(x2, p, -7.34990630326855e-04f);
  p = __builtin_fmaf(x2, p, -2.95459980854025e-03f);
  p = __builtin_fmaf(x2, p, -1.60960333262415e-02f);
  p = x * p;
  float q = __builtin_fmaf(x2, -1.45660718464996e-05f, -2.13374055278905e-04f);
  q = __builtin_fmaf(x2, q, -1.68282697438203e-03f);
  q = __builtin_fmaf(x2, q, -7.37332916720468e-03f);
  q = __builtin_fmaf(x2, q, -1.42647390514189e-02f);
  return p * fast_rcp(q);
}

// XLA chlo.erf_inv f32 (Giles polynomial) — phase 1 only, keep exact.
__device__ __forceinline__ float erfinv_xla(float x) {
  float w = -logf((1.0f - x) * (1.0f + x));
  float p;
  if (w < 5.0f) {
    w = w - 2.5f;
    p = 2.81022636e-08f;
    p = __builtin_fmaf(p, w, 3.43273939e-07f);
    p = __builtin_fmaf(p, w, -3.5233877e-06f);
    p = __builtin_fmaf(p, w, -4.39150654e-06f);
    p = __builtin_fmaf(p, w, 0.00021858087f);
    p = __builtin_fmaf(p, w, -0.00125372503f);
    p = __builtin_fmaf(p, w, -0.00417768164f);
    p = __builtin_fmaf(p, w, 0.246640727f);
    p = __builtin_fmaf(p, w, 1.50140941f);
  } else {
    w = sqrtf(w) - 3.0f;
    p = -0.000200214257f;
    p = __builtin_fmaf(p, w, 0.000100950558f);
    p = __builtin_fmaf(p, w, 0.00134934322f);
    p = __builtin_fmaf(p, w, -0.00367342844f);
    p = __builtin_fmaf(p, w, 0.00573950773f);
    p = __builtin_fmaf(p, w, -0.0076224613f);
    p = __builtin_fmaf(p, w, 0.00943887047f);
    p = __builtin_fmaf(p, w, 1.00167406f);
    p = __builtin_fmaf(p, w, 2.83297682f);
  }
  return p * x;
}

__device__ __forceinline__ float bits_to_normal(uint32_t bits) {
  const float MINVAL = -0.999999940395355224609375f;
  uint32_t fb = (bits >> 9) | 0x3F800000u;
  float f01 = __uint_as_float(fb) - 1.0f;
  float u = f01 * 2.0f + MINVAL;
  u = fmaxf(u, MINVAL);
  return 1.41421356237309515f * erfinv_xla(u);
}

__device__ __forceinline__ uint16_t f32_to_f16bits(float x) {
  _Float16 hv = (_Float16)x;  // RNE
  return __builtin_bit_cast(uint16_t, hv);
}

__device__ __forceinline__ uint32_t pack_f16x2(float lo, float hi) {
  return (uint32_t)f32_to_f16bits(lo) | ((uint32_t)f32_to_f16bits(hi) << 16);
}

// DPP add: v += dpp_move(v) — VALU pipe. 0x111..0x118 = row_shr 1..8.
template <int CTRL, int RMASK>
__device__ __forceinline__ float dpp_add(float v) {
  int x = __builtin_amdgcn_update_dpp(0, __float_as_int(v), CTRL, RMASK, 0xf, true);
  return v + __int_as_float(x);
}

// DPP move with explicit identity: lanes with no source keep OLD (bound=false).
template <int CTRL>
__device__ __forceinline__ float dpp_mov(float v, float old) {
  int x = __builtin_amdgcn_update_dpp(__float_as_int(old), __float_as_int(v),
                                      CTRL, 0xf, 0xf, false);
  return __int_as_float(x);
}

__device__ __forceinline__ float readlane_f(float v, int l) {
  return __int_as_float(__builtin_amdgcn_readlane(__float_as_int(v), l));
}

#define DTF  0.00396825396825396826f
#define SQDT 0.06299407883487120442f
#define TSTEP (1.0f / 2519.0f)
// tangents scaled by 64 for f16 headroom; coefficients fold the 1/64 back in
#define TSC      64.0f
#define TSC_INV  0.015625f
#define INV_SQRT2 0.7071067811865475f
#define PHI_C     0.3989422804014327f

// ---------------- Phase 1: mean_dW[b][s] — fully parallel ----------------
__global__ __launch_bounds__(256)
void vasicek_phase1_meandw(float* __restrict__ ws) {
  const int tid = threadIdx.x;
  const int lane = tid & 63;
  const int wv = tid >> 6;
  const int wid = blockIdx.x * 4 + wv;          // 0 .. 64*2520-1
  const int b = wid / NSTEPS;
  const int s = wid - b * NSTEPS;

  uint32_t kA, kB;
  tf2x32(0u, 1u, 0u, (uint32_t)s, kA, kB);      // split(key(1))[s]

  float sum = 0.f;
#pragma unroll
  for (int i = 0; i < 4; ++i) {
    uint32_t cnt = (uint32_t)(b * NQ + lane + i * 64);
    uint32_t q0, q1;
    tf2x32(kA, kB, 0u, cnt, q0, q1);
    float dw = bits_to_normal(q0 ^ q1) * SQDT;
    sum += dw;
  }
  sum += __shfl_xor(sum, 32, 64); sum += __shfl_xor(sum, 16, 64);
  sum += __shfl_xor(sum, 8, 64);  sum += __shfl_xor(sum, 4, 64);
  sum += __shfl_xor(sum, 2, 64);  sum += __shfl_xor(sum, 1, 64);
  if (lane == 0) ws[b * NSTEPS + s] = sum * (1.0f / 256.0f);
}

// ---- B-fragment machinery, k-PERMUTED (unchanged from R20):
// B dword d of K-chunk T (lane q,n) holds W2 rows (16T+4q+d, 64+16T+4q+d)
// at column 16*(4*half+C) + n, f16x2 packed.
#define BDECL(T, C) u32x4 b_##T##_##C;
#define BINIT(T, C) { \
  const int col_ = 16 * (4 * half + (C)) + n; \
  const int r0_ = 16 * (T) + 4 * q; \
  b_##T##_##C = (u32x4){ \
    pack_f16x2(W2src[(r0_ + 0) * 128 + col_], W2src[(r0_ + 64) * 128 + col_]), \
    pack_f16x2(W2src[(r0_ + 1) * 128 + col_], W2src[(r0_ + 65) * 128 + col_]), \
    pack_f16x2(W2src[(r0_ + 2) * 128 + col_], W2src[(r0_ + 66) * 128 + col_]), \
    pack_f16x2(W2src[(r0_ + 3) * 128 + col_], W2src[(r0_ + 67) * 128 + col_])}; \
  asm volatile("" : "+a"(b_##T##_##C)); /* pin in AGPR quad */ \
}
#define MFMA1(ACC, AF, BF) \
  asm("v_mfma_f32_16x16x32_f16 %0, %1, %2, %0" : "+v"(ACC) : "v"(AF), "a"(BF));

// layer-1 for step (J of batch), time TV, base = fma(anchor,w10,c1) hoisted;
// writes f16 halves of regions 2J (value) and 2J+1 (tangent*64).
#define STAGE3B(TV, SLOT, J) { \
  float pre_ = __builtin_fmaf((TV), w11, base); \
  float e_ = eigen_erf_fast(pre_ * INV_SQRT2); \
  float cg_ = (e_ + 1.0f) * 0.5f; \
  float v_ = pre_ * cg_; \
  float ph_ = PHI_C * __expf(-0.5f * pre_ * pre_); \
  float d_ = __builtin_fmaf(pre_, ph_, cg_) * w10S; \
  ((uint16_t*)&h1x[SLOT][mlp][2*(J)][0])[2 * lane + half] = f32_to_f16bits(v_); \
  ((uint16_t*)&h1x[SLOT][mlp][2*(J)+1][0])[2 * lane + half] = f32_to_f16bits(d_); \
}

// epilogue for one col-chunk: acc elems e = (step 2q+(e>>1), type e&1)
#define EPI(AC, BC, WC) { \
  float yv0 = AC[0] + (BC); float yt0 = AC[1]; \
  float yv1 = AC[2] + (BC); float yt1 = AC[3]; \
  float e0 = eigen_erf_fast(yv0 * INV_SQRT2); float c0_ = (e0 + 1.0f) * 0.5f; \
  float e1 = eigen_erf_fast(yv1 * INV_SQRT2); float c1_ = (e1 + 1.0f) * 0.5f; \
  pv0 = __builtin_fmaf((WC) * yv0, c0_, pv0); \
  pv1 = __builtin_fmaf((WC) * yv1, c1_, pv1); \
  float p0_ = PHI_C * __expf(-0.5f * yv0 * yv0); \
  float p1_ = PHI_C * __expf(-0.5f * yv1 * yv1); \
  float g0_ = __builtin_fmaf(yv0, p0_, c0_); \
  float g1_ = __builtin_fmaf(yv1, p1_, c1_); \
  pt0 = __builtin_fmaf((WC) * g0_, yt0, pt0); \
  pt1 = __builtin_fmaf((WC) * g1_, yt1, pt1); \
}

#define DPPROW(CTRL) { \
  pv0 = dpp_add<CTRL, 0xf>(pv0); pt0 = dpp_add<CTRL, 0xf>(pt0); \
  pv1 = dpp_add<CTRL, 0xf>(pv1); pt1 = dpp_add<CTRL, 0xf>(pt1); }

// ---------------- Phase 2: scan, 64 blocks x 256 ---------------------------
__global__
__attribute__((amdgpu_flat_work_group_size(256, 256)))
__attribute__((amdgpu_waves_per_eu(1, 1)))
void vasicek_phase2_scan(
    const float* __restrict__ X, const float* __restrict__ r_ult,
    const float* __restrict__ mats,
    const float* __restrict__ Wp, const float* __restrict__ bp,
    const float* __restrict__ ln_g, const float* __restrict__ ln_b,
    const float* __restrict__ muW1, const float* __restrict__ mub1,
    const float* __restrict__ muW2, const float* __restrict__ mub2,
    const float* __restrict__ muW3, const float* __restrict__ mub3,
    const float* __restrict__ siW1, const float* __restrict__ sib1,
    const float* __restrict__ siW2, const float* __restrict__ sib2,
    const float* __restrict__ siW3, const float* __restrict__ sib3,
    const float* __restrict__ ws, float* __restrict__ out) {
  // [slot][mlp][region n = 2*step+type][68 dw] (region stride 272B == 16 mod 128)
  __shared__ __align__(16) uint32_t h1x[2][2][16][68];
  __shared__ __align__(16) float meanw[MWPAD];
  __shared__ float part[256];
  __shared__ float mbuf[64];
  __shared__ float ctx_lds[192];
  __shared__ __align__(16) float msum[2][4][4][4];  // [slot][wave][q][pv0,pt0,pv1,pt1]

  const int t = threadIdx.x;
  const int b = blockIdx.x;
  const int lane = t & 63;
  const int wv = t >> 6;

  for (int i = t; i < MWPAD; i += 256)
    meanw[i] = i < NSTEPS ? ws[b * NSTEPS + i] : 0.f;

  // ---- context aggregator (all 256 threads, one T-row each) ----
  float h[64];
  {
    float x0 = X[(b * NT + t) * 2 + 0];
    float x1 = X[(b * NT + t) * 2 + 1];
    float s = 0.f;
#pragma unroll
    for (int c = 0; c < 64; ++c) {
      float pre = __builtin_fmaf(x1, Wp[64 + c], x0 * Wp[c]) + bp[c];
      h[c] = eigen_tanh(pre);
      s += h[c];
    }
    float m = s * 0.015625f;
    float vs = 0.f;
#pragma unroll
    for (int c = 0; c < 64; ++c) { float d = h[c] - m; vs = __builtin_fmaf(d, d, vs); }
    float den = sqrtf(vs * 0.015625f + 1e-5f);
#pragma unroll
    for (int c = 0; c < 64; ++c)
      h[c] = ((h[c] - m) / den) * ln_g[c] + ln_b[c];
  }
#pragma unroll
  for (int c = 0; c < 64; ++c) {
    float v = h[c];
    v += __shfl_xor(v, 32, 64); v += __shfl_xor(v, 16, 64);
    v += __shfl_xor(v, 8, 64);  v += __shfl_xor(v, 4, 64);
    v += __shfl_xor(v, 2, 64);  v += __shfl_xor(v, 1, 64);
    if (lane == 0) part[wv * 64 + c] = v;
  }
  __syncthreads();
  if (t < 64) {
    float m = ((part[t] + part[64 + t]) + (part[128 + t] + part[192 + t])) * (1.0f / 256.0f);
    mbuf[t] = m;
    ctx_lds[t] = m;
  }
  __syncthreads();
#pragma unroll
  for (int c = 0; c < 64; ++c) {
    float d = h[c] - mbuf[c];
    float v = d * d;
    v += __shfl_xor(v, 32, 64); v += __shfl_xor(v, 16, 64);
    v += __shfl_xor(v, 8, 64);  v += __shfl_xor(v, 4, 64);
    v += __shfl_xor(v, 2, 64);  v += __shfl_xor(v, 1, 64);
    if (lane == 0) part[wv * 64 + c] = v;
  }
  if (t == 255) {
#pragma unroll
    for (int c = 0; c < 64; ++c) ctx_lds[128 + c] = h[c];
  }
  __syncthreads();
  if (t < 64) {
    float vs = (part[t] + part[64 + t]) + (part[128 + t] + part[192 + t]);
    ctx_lds[64 + t] = sqrtf(vs / 255.0f);
  }
  __syncthreads();

  // ---- per-wave roles: mlp = wv>>1 (0=mu,1=si), half = wv&1 ----
  const int mlp = wv >> 1;
  const int half = wv & 1;
  const int jH = 64 * half + lane;            // layer-1 element ownership
  const float* W1 = mlp == 0 ? muW1 : siW1;
  const float* W2src = mlp == 0 ? muW2 : siW2;
  float c1 = (mlp == 0 ? mub1 : sib1)[jH];
  for (int c = 0; c < 192; ++c) {
    const float cx = ctx_lds[c];
    c1 = __builtin_fmaf(cx, W1[(2 + c) * 128 + jH], c1);
  }
  const float w10 = W1[jH], w11 = W1[128 + jH];
  const float w10S = w10 * TSC;
  const float b3mu = mub3[0], b3si = sib3[0];

  const int q = lane >> 4, n = lane & 15;

  // per-lane epilogue constants for its 4 col-chunks (col = 64*half+16C+n)
  const float* b2p = mlp == 0 ? mub2 : sib2;
  const float* w3p = mlp == 0 ? muW3 : siW3;
  const int colb = 64 * half + n;
  const float b2C0 = b2p[colb],      w3C0 = w3p[colb];
  const float b2C1 = b2p[colb + 16], w3C1 = w3p[colb + 16];
  const float b2C2 = b2p[colb + 32], w3C2 = w3p[colb + 32];
  const float b2C3 = b2p[colb + 48], w3C3 = w3p[colb + 48];

  // this wave's 4 col-tiles of its W2 -> 16 AGPR quads (one-time; pinned)
  BDECL(0,0) BDECL(0,1) BDECL(0,2) BDECL(0,3)
  BDECL(1,0) BDECL(1,1) BDECL(1,2) BDECL(1,3)
  BDECL(2,0) BDECL(2,1) BDECL(2,2) BDECL(2,3)
  BDECL(3,0) BDECL(3,1) BDECL(3,2) BDECL(3,3)
  BINIT(0,0) BINIT(0,1) BINIT(0,2) BINIT(0,3)
  BINIT(1,0) BINIT(1,1) BINIT(1,2) BINIT(1,3)
  BINIT(2,0) BINIT(2,1) BINIT(2,2) BINIT(2,3)
  BINIT(3,0) BINIT(3,1) BINIT(3,2) BINIT(3,3)

  // A-frag base pointers: region n of this wave's MLP, quad offset q.
  const u32x4* hq0 = ((const u32x4*)&h1x[0][mlp][0][0]) + 17 * n + q;
  const u32x4* hq1 = ((const u32x4*)&h1x[1][mlp][0][0]) + 17 * n + q;

  // ---- scan state: r + anchor queue as uniform floats; area per-lane ----
  const float r0 = r_ult[b];
  float r_s = r0;               // state before step 8(k) at body k (uniform)
  float aNow = r0, aUpd = r0, aMid = r0;  // anchors: batch k, k+1, k+2
  float area_p = 0.f;
  const int lj = lane & 7;
  const float mwo = (float)lj;  // unused placeholder (keeps lj alive)

  // ---- prologue: layer-1 for batch 0 (steps 0..7), anchor r0 -> slot 0 ----
  {
    float base = __builtin_fmaf(r0, w10, c1);
#pragma unroll
    for (int j = 0; j < 8; ++j) {
      const float tv0 = TSTEP * (float)j;
      STAGE3B(tv0, 0, j)
    }
  }
  __syncthreads();

  // ---- main loop: body k: scan batch k, MFMA batch k+1, STAGE3 batch k+2
#pragma unroll 1
  for (int k = -1; k < NBODY; ++k) {
    const int sl = k & 1;        // msum slot (batch k); h1 write slot (batch k+2)
    const int so = sl ^ 1;       // h1 read slot (batch k+1); msum write slot

    // --- LDS reads issued early ---
    const int jr = lj >> 1;
    f32x4 m0 = *(const f32x4*)&msum[sl][0][jr][0];   // mu wave 0 partials
    f32x4 m1 = *(const f32x4*)&msum[sl][1][jr][0];   // mu wave 1
    f32x4 m2 = *(const f32x4*)&msum[sl][2][jr][0];   // si wave 2
    f32x4 m3 = *(const f32x4*)&msum[sl][3][jr][0];   // si wave 3
    const int u0 = k < 0 ? 0 : 8 * k;
    const float mw = meanw[u0 + lj];                 // per-lane step meanw
    const u32x4* hq = so ? hq1 : hq0;
    u32x4 af0 = hq[0], af1 = hq[4], af2 = hq[8], af3 = hq[12];

    // --- MFMA batch k+1 (matrix pipe) ---
    f32x4 ac0 = {0,0,0,0}, ac1 = {0,0,0,0}, ac2 = {0,0,0,0}, ac3 = {0,0,0,0};
    MFMA1(ac0, af0, b_0_0) MFMA1(ac1, af0, b_0_1) MFMA1(ac2, af0, b_0_2) MFMA1(ac3, af0, b_0_3)
    MFMA1(ac0, af1, b_1_0) MFMA1(ac1, af1, b_1_1) MFMA1(ac2, af1, b_1_2) MFMA1(ac3, af1, b_1_3)
    MFMA1(ac0, af2, b_2_0) MFMA1(ac1, af2, b_2_1) MFMA1(ac2, af2, b_2_2) MFMA1(ac3, af2, b_2_3)
    MFMA1(ac0, af3, b_3_0) MFMA1(ac1, af3, b_3_1) MFMA1(ac2, af3, b_3_2) MFMA1(ac3, af3, b_3_3)

    // --- STAGE3 batch k+2 (anchor aMid from previous body; independent) ---
    {
      float base = __builtin_fmaf(aMid, w10, c1);
      const float tvb = TSTEP * (float)(8 * k + 16);
      STAGE3B(tvb + 0.0f * TSTEP, sl, 0) STAGE3B(tvb + 1.0f * TSTEP, sl, 1)
      STAGE3B(tvb + 2.0f * TSTEP, sl, 2) STAGE3B(tvb + 3.0f * TSTEP, sl, 3)
      STAGE3B(tvb + 4.0f * TSTEP, sl, 4) STAGE3B(tvb + 5.0f * TSTEP, sl, 5)
      STAGE3B(tvb + 6.0f * TSTEP, sl, 6) STAGE3B(tvb + 7.0f * TSTEP, sl, 7)
    }

    // --- affine scan for batch k (lane lj = step 8k+lj) ---
    {
      const bool odd = (lj & 1) != 0;
      float muv = (odd ? m0[2] : m0[0]) + (odd ? m1[2] : m1[0]);
      float mut = (odd ? m0[3] : m0[1]) + (odd ? m1[3] : m1[1]);
      float ziv = (odd ? m2[2] : m2[0]) + (odd ? m3[2] : m3[0]);
      float zit = (odd ? m2[3] : m2[1]) + (odd ? m3[3] : m3[1]);
      float mua = muv + b3mu;
      float mutp = mut * TSC_INV;
      float z = ziv + b3si;
      float sitp = zit * TSC_INV;
      // linearized softplus at z
      float e_ = __expf(-fabsf(z));
      float sp = fmaxf(z, 0.f) + __logf(1.0f + e_) + 1e-5f;
      float inv = fast_rcp(1.0f + e_);
      float sgm = z > 0.f ? inv : 1.0f - inv;
      float st = sgm * sitp;
      // beta, alpha (anchor aNow uniform)
      float beta = __builtin_fmaf(st, mw, __builtin_fmaf(mutp, DTF, 1.0f));
      float alpha = __builtin_fmaf(__builtin_fmaf(-aNow, mutp, mua), DTF,
                                   mw * __builtin_fmaf(-aNow, st, sp));
      // inclusive affine prefix scan over lanes 0..7 (row-local)
      float B = beta, A = alpha;
      {
        float Bs = dpp_mov<0x111>(B, 1.0f), As = dpp_mov<0x111>(A, 0.0f);
        A = __builtin_fmaf(B, As, A); B = B * Bs;
        Bs = dpp_mov<0x112>(B, 1.0f); As = dpp_mov<0x112>(A, 0.0f);
        A = __builtin_fmaf(B, As, A); B = B * Bs;
        Bs = dpp_mov<0x114>(B, 1.0f); As = dpp_mov<0x114>(A, 0.0f);
        A = __builtin_fmaf(B, As, A); B = B * Bs;
      }
      float rho = __builtin_fmaf(B, r_s, A);     // state after step 8k+lj
      if (k >= 0) {
        area_p = __builtin_fmaf(rho, DTF, area_p);
        // mu/si at step 7 for drift anchor prediction
        float rprev = dpp_mov<0x111>(rho, r_s);  // state before step (lane lj)
        float dru = rprev - aNow;
        float muj = __builtin_fmaf(mutp, dru, mua);
        float sij = __builtin_fmaf(st, dru, sp);
        (void)sij;
        float rn = readlane_f(rho, 7);
        float mu7 = readlane_f(muj, 7);
        // rotate anchors; new anchor = drift-only prediction for batch k+3
        // (steps 8k+24..31; midpoint distance 19.5 steps from rn)
        float aNew = __builtin_fmaf(mu7, 19.5f * DTF, rn);
        r_s = rn;
        aNow = aUpd; aUpd = aMid; aMid = aNew;
      }
    }

    // --- MFMA dst -> VALU read hazard fence ---
    asm volatile("s_nop 7\n\ts_nop 7"
                 : "+v"(ac0), "+v"(ac1), "+v"(ac2), "+v"(ac3));

    // --- epilogue batch k+1: gelu2 val+tan, per-row DPP reduce ---
    float pv0 = 0.f, pt0 = 0.f, pv1 = 0.f, pt1 = 0.f;
    EPI(ac0, b2C0, w3C0) EPI(ac1, b2C1, w3C1)
    EPI(ac2, b2C2, w3C2) EPI(ac3, b2C3, w3C3)
    DPPROW(0x111) DPPROW(0x112) DPPROW(0x114) DPPROW(0x118)
    if (n == 15) {
      *(f32x4*)&msum[so][wv][q][0] = (f32x4){pv0, pt0, pv1, pt1};
    }
    __syncthreads();  // publish msum[so] (batch k+1) + h1x[sl] (batch k+2)
  }

  // area: lanes 0..7 hold per-step-slot partials; reduce within 8-lane group
  float area = area_p;
  area += __shfl_xor(area, 1, 64);
  area += __shfl_xor(area, 2, 64);
  area += __shfl_xor(area, 4, 64);
  (void)mwo;

  if (t < NMAT) {
    float mx = mats[0];
#pragma unroll
    for (int i = 1; i < NMAT; ++i) mx = fmaxf(mx, mats[i]);
    const float mm = mats[t];
    const float frac = mm / (mx + 1e-12f);
    out[b * NMAT + t] = (area * frac) / (mm + 1e-12f);
  }
}

extern "C" void kernel_launch(void* const* d_in, const int* in_sizes, int n_in,
                              void* d_out, int out_size, void* d_ws, size_t ws_size,
                              hipStream_t stream) {
  (void)in_sizes; (void)n_in; (void)ws_size; (void)out_size;
  const float* X      = (const float*)d_in[0];
  const float* r_ult  = (const float*)d_in[1];
  const float* mats   = (const float*)d_in[2];
  const float* Wp     = (const float*)d_in[3];
  const float* bp     = (const float*)d_in[4];
  const float* ln_g   = (const float*)d_in[5];
  const float* ln_b   = (const float*)d_in[6];
  const float* muW1   = (const float*)d_in[7];
  const float* mub1   = (const float*)d_in[8];
  const float* muW2   = (const float*)d_in[9];
  const float* mub2   = (const float*)d_in[10];
  const float* muW3   = (const float*)d_in[11];
  const float* mub3   = (const float*)d_in[12];
  const float* siW1   = (const float*)d_in[13];
  const float* sib1   = (const float*)d_in[14];
  const float* siW2   = (const float*)d_in[15];
  const float* sib2   = (const float*)d_in[16];
  const float* siW3   = (const float*)d_in[17];
  const float* sib3   = (const float*)d_in[18];
  float* ws = (float*)d_ws;   // 64*2520*4 = 645,120 bytes

  hipLaunchKernelGGL(vasicek_phase1_meandw,
                     dim3(NB * NSTEPS / 4), dim3(256), 0, stream, ws);
  hipLaunchKernelGGL(vasicek_phase2_scan,
                     dim3(NB), dim3(256), 0, stream,
                     X, r_ult, mats, Wp, bp, ln_g, ln_b,
                     muW1, mub1, muW2, mub2, muW3, mub3,
                     siW1, sib1, siW2, sib2, siW3, sib3,
                     ws, (float*)d_out);
}

// Round 7
// 357.600 us; speedup vs baseline: 3.7300x; 2.0162x over previous
//
#include <hip/hip_runtime.h>
#include <stdint.h>

// ModeloNeuralVasicek — two-phase mean-recursion.
// Round 23: one-MLP-eval-per-batch. R22 (535us phase2) was VALU-op-count
// bound: 16 gelu/lane/body. Within a 16-step batch the value rows share one
// anchor and pre-activations vary only via t by <=2e-4 -> 2nd-order ~1e-8,
// far under f16 noise. So evaluate each MLP ONCE per batch with d/dr and
// d/dt tangents:
//  - A-rows: region n&3 in {val, dr*64, dt*1024, zero}; every q-group's
//    acc[0..2] = (val,dr,dt) col sums. 3 b16 LDS writes/lane/batch.
//  - EPI: lane (q,n) processes only chunk C=q -> 1 gelu2/lane/batch;
//    3 full-wave DPP reduces -> msum 3 floats/wave.
//  - scan: lane j=lane&15: mu_j = MV + jj*MT + (r-a)*MR; softplus linearized
//    at z_mid with 2nd-order jj correction; 4-round DPP affine scan.
//  - batch 16 -> 158 bodies (pad 2528; area masked), anchors drift-predicted
//    at distance 40.5 steps (tangent corrects; |r-a|~0.02 -> err ~4e-7).
// Phase1: logf -> __logf in erfinv (~1e-7 shift, negligible).

#define NSTEPS 2520
#define NB 64
#define NT 256
#define NQ 256
#define NMAT 7
#define NBODY 158
#define MWPAD 2576

typedef uint32_t u32x4 __attribute__((ext_vector_type(4)));
typedef float f32x4 __attribute__((ext_vector_type(4)));

__device__ __forceinline__ uint32_t rotl32(uint32_t v, int n) {
  return (v << n) | (v >> (32 - n));
}

// Threefry-2x32, 20 rounds — matches jax._src.prng.threefry2x32 exactly.
__device__ __forceinline__ void tf2x32(uint32_t k0, uint32_t k1,
                                       uint32_t x0, uint32_t x1,
                                       uint32_t& o0, uint32_t& o1) {
  const uint32_t k2 = k0 ^ k1 ^ 0x1BD11BDAu;
  x0 += k0; x1 += k1;
#define R4(a,b,c,d) \
  x0 += x1; x1 = rotl32(x1,(a)); x1 ^= x0; \
  x0 += x1; x1 = rotl32(x1,(b)); x1 ^= x0; \
  x0 += x1; x1 = rotl32(x1,(c)); x1 ^= x0; \
  x0 += x1; x1 = rotl32(x1,(d)); x1 ^= x0;
  R4(13,15,26,6)  x0 += k1; x1 += k2 + 1u;
  R4(17,29,16,24) x0 += k2; x1 += k0 + 2u;
  R4(13,15,26,6)  x0 += k0; x1 += k1 + 3u;
  R4(17,29,16,24) x0 += k1; x1 += k2 + 4u;
  R4(13,15,26,6)  x0 += k2; x1 += k0 + 5u;
#undef R4
  o0 = x0; o1 = x1;
}

// fast reciprocal: v_rcp + one Newton step (~1e-7 rel)
__device__ __forceinline__ float fast_rcp(float q) {
  float r = __builtin_amdgcn_rcpf(q);
  r = __builtin_fmaf(r, __builtin_fmaf(-q, r, 1.0f), r);
  return r;
}

// Eigen/XLA generic_fast_tanh_float (context aggregator only).
__device__ __forceinline__ float eigen_tanh(float a_x) {
  float x = fminf(fmaxf(a_x, -7.90531110763549805f), 7.90531110763549805f);
  float x2 = x * x;
  float p = __builtin_fmaf(x2, -2.76076847742355e-16f, 2.00018790482477e-13f);
  p = __builtin_fmaf(x2, p, -8.60467152213735e-11f);
  p = __builtin_fmaf(x2, p, 5.12229709037114e-08f);
  p = __builtin_fmaf(x2, p, 1.48572235717979e-05f);
  p = __builtin_fmaf(x2, p, 6.37261928875436e-04f);
  p = __builtin_fmaf(x2, p, 4.89352455891786e-03f);
  p = x * p;
  float q = __builtin_fmaf(x2, 1.19825839466702e-06f, 1.18534705686654e-04f);
  q = __builtin_fmaf(x2, q, 2.26843463243900e-03f);
  q = __builtin_fmaf(x2, q, 4.89352518554385e-03f);
  float rr = p / q;
  return (fabsf(a_x) < 0.0004f) ? a_x : rr;
}

// Eigen/XLA erf polynomial with rcp-division.
__device__ __forceinline__ float eigen_erf_fast(float a_x) {
  float x = fminf(fmaxf(a_x, -4.0f), 4.0f);
  float x2 = x * x;
  float p = __builtin_fmaf(x2, -2.72614225801306e-10f, 2.77068142495902e-08f);
  p = __builtin_fmaf(x2, p, -2.10102402082508e-06f);
  p = __builtin_fmaf(x2, p, -5.69250639462346e-05f);
  p = __builtin_fmaf(x2, p, -7.34990630326855e-04f);
  p = __builtin_fmaf(x2, p, -2.95459980854025e-03f);
  p = __builtin_fmaf(x2, p, -1.60960333262415e-02f);
  p = x * p;
  float q = __builtin_fmaf(x2, -1.45660718464996e-05f, -2.13374055278905e-04f);
  q = __builtin_fmaf(x2, q, -1.68282697438203e-03f);
  q = __builtin_fmaf(x2, q, -7.37332916720468e-03f);
  q = __builtin_fmaf(x2, q, -1.42647390514189e-02f);
  return p * fast_rcp(q);
}

// XLA chlo.erf_inv f32 — phase 1 only. __logf: ~1e-7 rel, negligible vs tol.
__device__ __forceinline__ float erfinv_xla(float x) {
  float w = -__logf((1.0f - x) * (1.0f + x));
  float p;
  if (w < 5.0f) {
    w = w - 2.5f;
    p = 2.81022636e-08f;
    p = __builtin_fmaf(p, w, 3.43273939e-07f);
    p = __builtin_fmaf(p, w, -3.5233877e-06f);
    p = __builtin_fmaf(p, w, -4.39150654e-06f);
    p = __builtin_fmaf(p, w, 0.00021858087f);
    p = __builtin_fmaf(p, w, -0.00125372503f);
    p = __builtin_fmaf(p, w, -0.00417768164f);
    p = __builtin_fmaf(p, w, 0.246640727f);
    p = __builtin_fmaf(p, w, 1.50140941f);
  } else {
    w = sqrtf(w) - 3.0f;
    p = -0.000200214257f;
    p = __builtin_fmaf(p, w, 0.000100950558f);
    p = __builtin_fmaf(p, w, 0.00134934322f);
    p = __builtin_fmaf(p, w, -0.00367342844f);
    p = __builtin_fmaf(p, w, 0.00573950773f);
    p = __builtin_fmaf(p, w, -0.0076224613f);
    p = __builtin_fmaf(p, w, 0.00943887047f);
    p = __builtin_fmaf(p, w, 1.00167406f);
    p = __builtin_fmaf(p, w, 2.83297682f);
  }
  return p * x;
}

__device__ __forceinline__ float bits_to_normal(uint32_t bits) {
  const float MINVAL = -0.999999940395355224609375f;
  uint32_t fb = (bits >> 9) | 0x3F800000u;
  float f01 = __uint_as_float(fb) - 1.0f;
  float u = f01 * 2.0f + MINVAL;
  u = fmaxf(u, MINVAL);
  return 1.41421356237309515f * erfinv_xla(u);
}

__device__ __forceinline__ uint16_t f32_to_f16bits(float x) {
  _Float16 hv = (_Float16)x;  // RNE
  return __builtin_bit_cast(uint16_t, hv);
}

__device__ __forceinline__ uint32_t pack_f16x2(float lo, float hi) {
  return (uint32_t)f32_to_f16bits(lo) | ((uint32_t)f32_to_f16bits(hi) << 16);
}

// DPP add: v += dpp_move(v) — VALU pipe. 0x111..0x118 row_shr; 0x142/0x143 bcast.
template <int CTRL, int RMASK>
__device__ __forceinline__ float dpp_add(float v) {
  int x = __builtin_amdgcn_update_dpp(0, __float_as_int(v), CTRL, RMASK, 0xf, true);
  return v + __int_as_float(x);
}

// full-wave sum -> lane 63 (R15/R17/R18-validated chain)
__device__ __forceinline__ float dpp_reduce63(float p) {
  p = dpp_add<0x111, 0xf>(p);
  p = dpp_add<0x112, 0xf>(p);
  p = dpp_add<0x114, 0xf>(p);
  p = dpp_add<0x118, 0xf>(p);
  p = dpp_add<0x142, 0xa>(p);
  p = dpp_add<0x143, 0xc>(p);
  return p;
}

// DPP move with explicit identity (bound_ctrl=false keeps OLD for no-src lanes)
template <int CTRL>
__device__ __forceinline__ float dpp_mov(float v, float old) {
  int x = __builtin_amdgcn_update_dpp(__float_as_int(old), __float_as_int(v),
                                      CTRL, 0xf, 0xf, false);
  return __int_as_float(x);
}

__device__ __forceinline__ float readlane_f(float v, int l) {
  return __int_as_float(__builtin_amdgcn_readlane(__float_as_int(v), l));
}

#define DTF  0.00396825396825396826f
#define SQDT 0.06299407883487120442f
#define TSTEP (1.0f / 2519.0f)
#define TSC      64.0f
#define TSC_INV  0.015625f
#define TSC_T    1024.0f
#define TSCT_INV 0.0009765625f
#define INV_SQRT2 0.7071067811865475f
#define PHI_C     0.3989422804014327f

// ---------------- Phase 1: mean_dW[b][s] — fully parallel ----------------
__global__ __launch_bounds__(256)
void vasicek_phase1_meandw(float* __restrict__ ws) {
  const int tid = threadIdx.x;
  const int lane = tid & 63;
  const int wv = tid >> 6;
  const int wid = blockIdx.x * 4 + wv;          // 0 .. 64*2520-1
  const int b = wid / NSTEPS;
  const int s = wid - b * NSTEPS;

  uint32_t kA, kB;
  tf2x32(0u, 1u, 0u, (uint32_t)s, kA, kB);      // split(key(1))[s]

  float sum = 0.f;
#pragma unroll
  for (int i = 0; i < 4; ++i) {
    uint32_t cnt = (uint32_t)(b * NQ + lane + i * 64);
    uint32_t q0, q1;
    tf2x32(kA, kB, 0u, cnt, q0, q1);
    float dw = bits_to_normal(q0 ^ q1) * SQDT;
    sum += dw;
  }
  sum += __shfl_xor(sum, 32, 64); sum += __shfl_xor(sum, 16, 64);
  sum += __shfl_xor(sum, 8, 64);  sum += __shfl_xor(sum, 4, 64);
  sum += __shfl_xor(sum, 2, 64);  sum += __shfl_xor(sum, 1, 64);
  if (lane == 0) ws[b * NSTEPS + s] = sum * (1.0f / 256.0f);
}

// ---- B-fragment machinery, k-PERMUTED (unchanged from R20/R22):
// B dword d of K-chunk T (lane q,n) holds W2 rows (16T+4q+d, 64+16T+4q+d)
// at column 16*(4*half+C) + n, f16x2 packed.
#define BDECL(T, C) u32x4 b_##T##_##C;
#define BINIT(T, C) { \
  const int col_ = 16 * (4 * half + (C)) + n; \
  const int r0_ = 16 * (T) + 4 * q; \
  b_##T##_##C = (u32x4){ \
    pack_f16x2(W2src[(r0_ + 0) * 128 + col_], W2src[(r0_ + 64) * 128 + col_]), \
    pack_f16x2(W2src[(r0_ + 1) * 128 + col_], W2src[(r0_ + 65) * 128 + col_]), \
    pack_f16x2(W2src[(r0_ + 2) * 128 + col_], W2src[(r0_ + 66) * 128 + col_]), \
    pack_f16x2(W2src[(r0_ + 3) * 128 + col_], W2src[(r0_ + 67) * 128 + col_])}; \
  asm volatile("" : "+a"(b_##T##_##C)); /* pin in AGPR quad */ \
}
#define MFMA1(ACC, AF, BF) \
  asm("v_mfma_f32_16x16x32_f16 %0, %1, %2, %0" : "+v"(ACC) : "v"(AF), "a"(BF));

// one-eval layer-1 for a batch: anchor A_, mid-time TV; writes regions
// 0=val, 1=d/dr*64, 2=d/dt_j*1024 (region 3 pre-zeroed).
#define STAGE3M(TV, SLOT, A_) { \
  float pre_ = __builtin_fmaf((TV), w11, __builtin_fmaf((A_), w10, c1)); \
  float e_ = eigen_erf_fast(pre_ * INV_SQRT2); \
  float cg_ = (e_ + 1.0f) * 0.5f; \
  float v_ = pre_ * cg_; \
  float ph_ = PHI_C * __expf(-0.5f * pre_ * pre_); \
  float gp_ = __builtin_fmaf(pre_, ph_, cg_); \
  ((uint16_t*)&h1x[SLOT][mlp][0][0])[2 * lane + half] = f32_to_f16bits(v_); \
  ((uint16_t*)&h1x[SLOT][mlp][1][0])[2 * lane + half] = f32_to_f16bits(gp_ * w10S); \
  ((uint16_t*)&h1x[SLOT][mlp][2][0])[2 * lane + half] = f32_to_f16bits(gp_ * w11T); \
}

// ---------------- Phase 2: scan, 64 blocks x 256 ---------------------------
__global__
__attribute__((amdgpu_flat_work_group_size(256, 256)))
__attribute__((amdgpu_waves_per_eu(1, 1)))
void vasicek_phase2_scan(
    const float* __restrict__ X, const float* __restrict__ r_ult,
    const float* __restrict__ mats,
    const float* __restrict__ Wp, const float* __restrict__ bp,
    const float* __restrict__ ln_g, const float* __restrict__ ln_b,
    const float* __restrict__ muW1, const float* __restrict__ mub1,
    const float* __restrict__ muW2, const float* __restrict__ mub2,
    const float* __restrict__ muW3, const float* __restrict__ mub3,
    const float* __restrict__ siW1, const float* __restrict__ sib1,
    const float* __restrict__ siW2, const float* __restrict__ sib2,
    const float* __restrict__ siW3, const float* __restrict__ sib3,
    const float* __restrict__ ws, float* __restrict__ out) {
  // [slot][mlp][region: 0=val,1=dr,2=dt,3=zero][68 dw] (stride 272B==16 mod 128)
  __shared__ __align__(16) uint32_t h1x[2][2][4][68];
  __shared__ __align__(16) float meanw[MWPAD];
  __shared__ float part[256];
  __shared__ float mbuf[64];
  __shared__ float ctx_lds[192];
  __shared__ __align__(16) float msum[2][4][4];   // [slot][wave][PV,PR,PT,pad]

  const int t = threadIdx.x;
  const int b = blockIdx.x;
  const int lane = t & 63;
  const int wv = t >> 6;

  for (int i = t; i < MWPAD; i += 256)
    meanw[i] = i < NSTEPS ? ws[b * NSTEPS + i] : 0.f;

  // ---- context aggregator (all 256 threads, one T-row each) ----
  float h[64];
  {
    float x0 = X[(b * NT + t) * 2 + 0];
    float x1 = X[(b * NT + t) * 2 + 1];
    float s = 0.f;
#pragma unroll
    for (int c = 0; c < 64; ++c) {
      float pre = __builtin_fmaf(x1, Wp[64 + c], x0 * Wp[c]) + bp[c];
      h[c] = eigen_tanh(pre);
      s += h[c];
    }
    float m = s * 0.015625f;
    float vs = 0.f;
#pragma unroll
    for (int c = 0; c < 64; ++c) { float d = h[c] - m; vs = __builtin_fmaf(d, d, vs); }
    float den = sqrtf(vs * 0.015625f + 1e-5f);
#pragma unroll
    for (int c = 0; c < 64; ++c)
      h[c] = ((h[c] - m) / den) * ln_g[c] + ln_b[c];
  }
#pragma unroll
  for (int c = 0; c < 64; ++c) {
    float v = h[c];
    v += __shfl_xor(v, 32, 64); v += __shfl_xor(v, 16, 64);
    v += __shfl_xor(v, 8, 64);  v += __shfl_xor(v, 4, 64);
    v += __shfl_xor(v, 2, 64);  v += __shfl_xor(v, 1, 64);
    if (lane == 0) part[wv * 64 + c] = v;
  }
  __syncthreads();
  if (t < 64) {
    float m = ((part[t] + part[64 + t]) + (part[128 + t] + part[192 + t])) * (1.0f / 256.0f);
    mbuf[t] = m;
    ctx_lds[t] = m;
  }
  __syncthreads();
#pragma unroll
  for (int c = 0; c < 64; ++c) {
    float d = h[c] - mbuf[c];
    float v = d * d;
    v += __shfl_xor(v, 32, 64); v += __shfl_xor(v, 16, 64);
    v += __shfl_xor(v, 8, 64);  v += __shfl_xor(v, 4, 64);
    v += __shfl_xor(v, 2, 64);  v += __shfl_xor(v, 1, 64);
    if (lane == 0) part[wv * 64 + c] = v;
  }
  if (t == 255) {
#pragma unroll
    for (int c = 0; c < 64; ++c) ctx_lds[128 + c] = h[c];
  }
  __syncthreads();
  if (t < 64) {
    float vs = (part[t] + part[64 + t]) + (part[128 + t] + part[192 + t]);
    ctx_lds[64 + t] = sqrtf(vs / 255.0f);
  }
  __syncthreads();

  // ---- per-wave roles: mlp = wv>>1 (0=mu,1=si), half = wv&1 ----
  const int mlp = wv >> 1;
  const int half = wv & 1;
  const int jH = 64 * half + lane;            // layer-1 element ownership
  const float* W1 = mlp == 0 ? muW1 : siW1;
  const float* W2src = mlp == 0 ? muW2 : siW2;
  float c1 = (mlp == 0 ? mub1 : sib1)[jH];
  for (int c = 0; c < 192; ++c) {
    const float cx = ctx_lds[c];
    c1 = __builtin_fmaf(cx, W1[(2 + c) * 128 + jH], c1);
  }
  const float w10 = W1[jH], w11 = W1[128 + jH];
  const float w10S = w10 * TSC;
  const float w11T = w11 * (TSTEP * TSC_T);
  const float b3mu = mub3[0], b3si = sib3[0];

  const int q = lane >> 4, n = lane & 15;

  // per-lane epilogue constants: this lane's single column (chunk C = q)
  const float* b2p = mlp == 0 ? mub2 : sib2;
  const float* w3p = mlp == 0 ? muW3 : siW3;
  const int colE = 64 * half + 16 * q + n;
  const float b2E = b2p[colE], w3E = w3p[colE];

  // this wave's 4 col-tiles of its W2 -> 16 AGPR quads (one-time; pinned)
  BDECL(0,0) BDECL(0,1) BDECL(0,2) BDECL(0,3)
  BDECL(1,0) BDECL(1,1) BDECL(1,2) BDECL(1,3)
  BDECL(2,0) BDECL(2,1) BDECL(2,2) BDECL(2,3)
  BDECL(3,0) BDECL(3,1) BDECL(3,2) BDECL(3,3)
  BINIT(0,0) BINIT(0,1) BINIT(0,2) BINIT(0,3)
  BINIT(1,0) BINIT(1,1) BINIT(1,2) BINIT(1,3)
  BINIT(2,0) BINIT(2,1) BINIT(2,2) BINIT(2,3)
  BINIT(3,0) BINIT(3,1) BINIT(3,2) BINIT(3,3)

  // zero region 3 (A-rows 3,7,11,15) for both slots of this wave's MLP
  h1x[0][mlp][3][lane] = 0u; h1x[1][mlp][3][lane] = 0u;
  if (lane < 4) { h1x[0][mlp][3][64 + lane] = 0u; h1x[1][mlp][3][64 + lane] = 0u; }

  // A-frag base pointers: region (n&3) of this wave's MLP, quad offset q.
  const u32x4* hq0 = ((const u32x4*)&h1x[0][mlp][0][0]) + 17 * (n & 3) + q;
  const u32x4* hq1 = ((const u32x4*)&h1x[1][mlp][0][0]) + 17 * (n & 3) + q;

  // ---- scan state (uniform) + per-lane area ----
  const float r0 = r_ult[b];
  float r_s = r0;
  float aNow = r0, aUpd = r0, aMid = r0;   // anchors: batch k, k+1, k+2
  float area_p = 0.f;
  const int sj = lane & 15;                // step-in-batch for scan
  const float jj = (float)sj - 7.5f;

  // ---- prologue: layer-1 one-eval for batch 0 -> slot 0, anchor r0 ----
  STAGE3M(TSTEP * 7.5f, 0, r0)
  __syncthreads();

  // ---- main loop: body k: scan batch k, MFMA batch k+1, STAGE3 batch k+2
#pragma unroll 1
  for (int k = -1; k < NBODY; ++k) {
    const int sl = k & 1;        // msum slot (batch k); h1 write slot (batch k+2)
    const int so = sl ^ 1;       // h1 read slot (batch k+1); msum write slot

    // --- LDS reads issued early ---
    f32x4 m0 = *(const f32x4*)&msum[sl][0][0];
    f32x4 m1 = *(const f32x4*)&msum[sl][1][0];
    f32x4 m2 = *(const f32x4*)&msum[sl][2][0];
    f32x4 m3 = *(const f32x4*)&msum[sl][3][0];
    const int u0 = k < 0 ? 0 : 16 * k;
    const float mwj = meanw[u0 + sj];
    const u32x4* hq = so ? hq1 : hq0;
    u32x4 af0 = hq[0], af1 = hq[4], af2 = hq[8], af3 = hq[12];

    // --- MFMA batch k+1 (matrix pipe) ---
    f32x4 ac0 = {0,0,0,0}, ac1 = {0,0,0,0}, ac2 = {0,0,0,0}, ac3 = {0,0,0,0};
    MFMA1(ac0, af0, b_0_0) MFMA1(ac1, af0, b_0_1) MFMA1(ac2, af0, b_0_2) MFMA1(ac3, af0, b_0_3)
    MFMA1(ac0, af1, b_1_0) MFMA1(ac1, af1, b_1_1) MFMA1(ac2, af1, b_1_2) MFMA1(ac3, af1, b_1_3)
    MFMA1(ac0, af2, b_2_0) MFMA1(ac1, af2, b_2_1) MFMA1(ac2, af2, b_2_2) MFMA1(ac3, af2, b_2_3)
    MFMA1(ac0, af3, b_3_0) MFMA1(ac1, af3, b_3_1) MFMA1(ac2, af3, b_3_2) MFMA1(ac3, af3, b_3_3)

    // --- STAGE3 batch k+2 (anchor aMid from previous body; independent) ---
    STAGE3M(TSTEP * ((float)(16 * (k + 2)) + 7.5f), sl, aMid)

    // --- affine scan for batch k (lane sj = step 16k+sj) ---
    {
      float MV = (m0[0] + m1[0]) + b3mu;
      float MR = (m0[1] + m1[1]) * TSC_INV;
      float MT = (m0[2] + m1[2]) * TSCT_INV;
      float ZV = (m2[0] + m3[0]) + b3si;
      float ZR = (m2[1] + m3[1]) * TSC_INV;
      float ZT = (m2[2] + m3[2]) * TSCT_INV;
      // softplus at z_mid + 2nd-order in the (r-independent) time offset
      float e_ = __expf(-fabsf(ZV));
      float sp = fmaxf(ZV, 0.f) + __logf(1.0f + e_) + 1e-5f;
      float inv = fast_rcp(1.0f + e_);
      float sgm = ZV > 0.f ? inv : 1.0f - inv;
      float hcv = 0.5f * sgm * (1.0f - sgm);
      float dzt = jj * ZT;
      float sigj = __builtin_fmaf(2.0f * hcv, dzt, sgm);    // sigma(z_mid+dzt)
      float spj  = __builtin_fmaf(__builtin_fmaf(hcv, dzt, sgm), dzt, sp);
      float sZR = sigj * ZR;
      // beta, alpha
      float beta = __builtin_fmaf(sZR, mwj, __builtin_fmaf(MR, DTF, 1.0f));
      float am_ = __builtin_fmaf(jj, MT, __builtin_fmaf(-aNow, MR, MV));
      float as_ = __builtin_fmaf(-aNow, sZR, spj);
      float alpha = __builtin_fmaf(am_, DTF, as_ * mwj);
      // inclusive affine prefix scan over the 16-lane row
      float B = beta, A = alpha;
      {
        float Bs = dpp_mov<0x111>(B, 1.0f), As = dpp_mov<0x111>(A, 0.0f);
        A = __builtin_fmaf(B, As, A); B = B * Bs;
        Bs = dpp_mov<0x112>(B, 1.0f); As = dpp_mov<0x112>(A, 0.0f);
        A = __builtin_fmaf(B, As, A); B = B * Bs;
        Bs = dpp_mov<0x114>(B, 1.0f); As = dpp_mov<0x114>(A, 0.0f);
        A = __builtin_fmaf(B, As, A); B = B * Bs;
        Bs = dpp_mov<0x118>(B, 1.0f); As = dpp_mov<0x118>(A, 0.0f);
        A = __builtin_fmaf(B, As, A); B = B * Bs;
      }
      float rho = __builtin_fmaf(B, r_s, A);
      if (k >= 0) {
        float contrib = (16 * k + sj) < NSTEPS ? rho * DTF : 0.f;
        area_p += contrib;
        float rn = readlane_f(rho, 15);
        // drift-only prediction for batch k+3 (mid-step distance ~40.5)
        float aNew = __builtin_fmaf(MV, 40.5f * DTF, rn);
        r_s = rn;
        aNow = aUpd; aUpd = aMid; aMid = aNew;
      }
    }

    // --- MFMA dst -> VALU read hazard fence ---
    asm volatile("s_nop 7\n\ts_nop 7"
                 : "+v"(ac0), "+v"(ac1), "+v"(ac2), "+v"(ac3));

    // --- epilogue batch k+1: lane (q,n) handles its single column (C=q) ---
    {
      const f32x4 aq = q == 0 ? ac0 : q == 1 ? ac1 : q == 2 ? ac2 : ac3;
      float yv = aq[0] + b2E;
      float ytr = aq[1];                 // d/dr row (scaled TSC)
      float ytt = aq[2];                 // d/dt row (scaled TSC_T)
      float ev = eigen_erf_fast(yv * INV_SQRT2);
      float cv = (ev + 1.0f) * 0.5f;
      float pv = yv * cv * w3E;
      float phv = PHI_C * __expf(-0.5f * yv * yv);
      float g2p = __builtin_fmaf(yv, phv, cv) * w3E;
      float pr = g2p * ytr;
      float pt = g2p * ytt;
      pv = dpp_reduce63(pv);
      pr = dpp_reduce63(pr);
      pt = dpp_reduce63(pt);
      if (lane == 63) {
        *(f32x4*)&msum[so][wv][0] = (f32x4){pv, pr, pt, 0.f};
      }
    }
    __syncthreads();  // publish msum[so] (batch k+1) + h1x[sl] (batch k+2)
  }

  // area: each 16-lane row holds per-step partials (replicated across rows)
  float area = area_p;
  area += __shfl_xor(area, 1, 64);
  area += __shfl_xor(area, 2, 64);
  area += __shfl_xor(area, 4, 64);
  area += __shfl_xor(area, 8, 64);

  if (t < NMAT) {
    float mx = mats[0];
#pragma unroll
    for (int i = 1; i < NMAT; ++i) mx = fmaxf(mx, mats[i]);
    const float mm = mats[t];
    const float frac = mm / (mx + 1e-12f);
    out[b * NMAT + t] = (area * frac) / (mm + 1e-12f);
  }
}

extern "C" void kernel_launch(void* const* d_in, const int* in_sizes, int n_in,
                              void* d_out, int out_size, void* d_ws, size_t ws_size,
                              hipStream_t stream) {
  (void)in_sizes; (void)n_in; (void)ws_size; (void)out_size;
  const float* X      = (const float*)d_in[0];
  const float* r_ult  = (const float*)d_in[1];
  const float* mats   = (const float*)d_in[2];
  const float* Wp     = (const float*)d_in[3];
  const float* bp     = (const float*)d_in[4];
  const float* ln_g   = (const float*)d_in[5];
  const float* ln_b   = (const float*)d_in[6];
  const float* muW1   = (const float*)d_in[7];
  const float* mub1   = (const float*)d_in[8];
  const float* muW2   = (const float*)d_in[9];
  const float* mub2   = (const float*)d_in[10];
  const float* muW3   = (const float*)d_in[11];
  const float* mub3   = (const float*)d_in[12];
  const float* siW1   = (const float*)d_in[13];
  const float* sib1   = (const float*)d_in[14];
  const float* siW2   = (const float*)d_in[15];
  const float* sib2   = (const float*)d_in[16];
  const float* siW3   = (const float*)d_in[17];
  const float* sib3   = (const float*)d_in[18];
  float* ws = (float*)d_ws;   // 64*2520*4 = 645,120 bytes

  hipLaunchKernelGGL(vasicek_phase1_meandw,
                     dim3(NB * NSTEPS / 4), dim3(256), 0, stream, ws);
  hipLaunchKernelGGL(vasicek_phase2_scan,
                     dim3(NB), dim3(256), 0, stream,
                     X, r_ult, mats, Wp, bp, ln_g, ln_b,
                     muW1, mub1, muW2, mub2, muW3, mub3,
                     siW1, sib1, siW2, sib2, siW3, sib3,
                     ws, (float*)d_out);
}